// Round 14
// baseline (7576.796 us; speedup 1.0000x reference)
//
#include <hip/hip_runtime.h>
#include <hip/hip_bf16.h>

typedef _Float16 f16;
typedef _Float16 half8 __attribute__((ext_vector_type(8)));
typedef float f32x4 __attribute__((ext_vector_type(4)));
typedef int i32x4 __attribute__((ext_vector_type(4)));

// B=32, S=1024, D=256, H=256, 4H=1024
// Scan r14 (dir-fused): 32 WGs = one per batch; each WG advances BOTH the fwd
// and rev chains each iteration. MFMA_f + MFMA_r issue back-to-back on the
// matrix pipe; the fwd epilogue's serial tail (bpermute+exp chain) overlaps
// MFMA_r. One lgkm barrier per iteration. U for both dirs = 128 MFMA-B regs
// (AGPR-native). Epilogue = r10/r12-verified quad_perm scheme.

// ---------------- prep: per-column int8 quantization of U (mfma layout) -----
// UQm uint4 index: ((dir*64 + tile)*4 + ks)*64 + kg*16 + colr
//   holds k = ks*64 + kg*16 + {0..15} (16 int8) for col = tile*16 + colr.
__global__ void prep_uq_kernel(const float* __restrict__ Uf, const float* __restrict__ Ur,
                               unsigned int* __restrict__ UQm, float* __restrict__ Uscale)
{
    int idx = blockIdx.x * 256 + threadIdx.x;   // (dir, c)
    if (idx >= 2048) return;
    int dir = idx >> 10, c = idx & 1023;
    const float* U = dir ? Ur : Uf;
    float m = 0.f;
    for (int k = 0; k < 256; ++k) m = fmaxf(m, fabsf(U[k * 1024 + c]));
    float sinv = (m > 0.f) ? 127.f / m : 0.f;
    int tile = c >> 4, colr = c & 15;
    uint4* UQm4 = (uint4*)UQm;
    for (int ks = 0; ks < 4; ++ks) {
        #pragma unroll
        for (int kg = 0; kg < 4; ++kg) {
            unsigned int w[4];
            #pragma unroll
            for (int d = 0; d < 4; ++d) {
                unsigned int wd = 0;
                #pragma unroll
                for (int e = 0; e < 4; ++e) {
                    int k = ks * 64 + kg * 16 + d * 4 + e;
                    int q = __float2int_rn(U[k * 1024 + c] * sinv);
                    wd |= ((unsigned int)(q & 0xff)) << (8 * e);
                }
                w[d] = wd;
            }
            UQm4[((size_t)((dir * 64 + tile) * 4 + ks)) * 64 + kg * 16 + colr] =
                make_uint4(w[0], w[1], w[2], w[3]);
        }
    }
    Uscale[idx] = m / (127.f * 127.f);  // U-scale * h-dequant(1/127)
}

// ---------------- projection GEMM (unchanged, proven) -----------------------
__global__ __launch_bounds__(256) void proj_gemm_kernel(
    const float* __restrict__ x, const float* __restrict__ Wf, const float* __restrict__ Wr,
    const float* __restrict__ bfw, const float* __restrict__ brw, f16* __restrict__ G)
{
    const int nt = blockIdx.x;
    const int mt = blockIdx.y;
    const int m0 = mt * 128, n0 = nt * 128;
    const int dir = n0 >> 10, nin0 = n0 & 1023;
    const float* W   = dir ? Wr : Wf;
    const float* bia = dir ? brw : bfw;
    __shared__ f16 Asm[128][40];
    __shared__ f16 Bsm[128][40];
    const int t = threadIdx.x;
    const int lane = t & 63, wave = t >> 6;
    const int wr = wave >> 1, wc = wave & 1;
    f32x4 acc[4][4] = {};
    for (int k0 = 0; k0 < 256; k0 += 32) {
        #pragma unroll
        for (int e = 0; e < 16; ++e) {
            int idx = e * 256 + t;
            int r = idx >> 5, kk = idx & 31;
            Asm[r][kk] = (f16)x[(size_t)(m0 + r) * 256 + (k0 + kk)];
        }
        #pragma unroll
        for (int e = 0; e < 16; ++e) {
            int idx = e * 256 + t;
            int col = idx & 127, kr = idx >> 7;
            Bsm[col][kr] = (f16)W[(size_t)(k0 + kr) * 1024 + (nin0 + col)];
        }
        __syncthreads();
        const int l15 = lane & 15, kb = (lane >> 4) * 8;
        half8 af[4], bfr[4];
        #pragma unroll
        for (int fr = 0; fr < 4; ++fr) af[fr]  = *(const half8*)&Asm[wr * 64 + fr * 16 + l15][kb];
        #pragma unroll
        for (int fc = 0; fc < 4; ++fc) bfr[fc] = *(const half8*)&Bsm[wc * 64 + fc * 16 + l15][kb];
        #pragma unroll
        for (int fr = 0; fr < 4; ++fr)
            #pragma unroll
            for (int fc = 0; fc < 4; ++fc)
                acc[fr][fc] = __builtin_amdgcn_mfma_f32_16x16x32_f16(af[fr], bfr[fc], acc[fr][fc], 0, 0, 0);
        __syncthreads();
    }
    const int row4 = (lane >> 4) * 4, c15 = lane & 15;
    #pragma unroll
    for (int fr = 0; fr < 4; ++fr)
        #pragma unroll
        for (int fc = 0; fc < 4; ++fc) {
            int rbase = m0 + wr * 64 + fr * 16 + row4;
            int cidx  = n0 + wc * 64 + fc * 16 + c15;
            float bv = bia[cidx & 1023];
            #pragma unroll
            for (int i = 0; i < 4; ++i)
                G[(size_t)(rbase + i) * 2048 + cidx] = (f16)(acc[fr][fc][i] + bv);
        }
}

// ---------------- scan ------------------------------------------------------
template<int PAT>
__device__ __forceinline__ float qb(float v) {   // quad_perm broadcast
    return __int_as_float(__builtin_amdgcn_mov_dpp(__float_as_int(v), PAT, 0xF, 0xF, true));
}

#define LGKM_BARRIER() do { \
    asm volatile("s_waitcnt lgkmcnt(0)\n\ts_barrier" ::: "memory"); \
    __builtin_amdgcn_sched_barrier(0); \
} while (0)

__global__
__attribute__((amdgpu_flat_work_group_size(1024, 1024)))
__attribute__((amdgpu_waves_per_eu(4, 4)))
void scan_kernel(
    const f16* __restrict__ G, const unsigned int* __restrict__ UQm,
    const float* __restrict__ Uscale, float* __restrict__ out)
{
    const int b = blockIdx.x;                       // batch (32 WGs)
    const int tid = threadIdx.x;
    const int wave = tid >> 6, lane = tid & 63;
    const int colq = lane >> 2, gate = lane & 3;    // lane -> (col, gate)
    const int mycol = wave * 16 + colq;

    // LDS: h int8[256] per dir, double-buffered: byte offset dir*512 + p*256
    __shared__ __align__(16) unsigned int hq[256];
    if (tid < 64)  hq[tid] = 0u;                    // fwd buf0 = 0
    if (tid >= 64 && tid < 192 && tid >= 128) hq[tid] = 0u;  // rev buf0 (words 128..191)

    // B-fragments for both dirs: gate g -> tile g*16+wave. 2x64 regs, AGPR-ok.
    const i32x4* UQm4 = (const i32x4*)UQm;
    i32x4 uff[16], ufr[16];
    #pragma unroll
    for (int g = 0; g < 4; ++g)
        #pragma unroll
        for (int ks = 0; ks < 4; ++ks) {
            uff[g * 4 + ks] = UQm4[((size_t)((      g * 16 + wave) * 4 + ks)) * 64 + lane];
            ufr[g * 4 + ks] = UQm4[((size_t)((64 +  g * 16 + wave) * 4 + ks)) * 64 + lane];
        }

    const float uscf = Uscale[       gate * 256 + mycol];
    const float uscr = Uscale[1024 + gate * 256 + mycol];

    // per-lane xW streams: fwd reads s=t, rev reads s=1023-t
    const f16* Gf = G + (size_t)b * 1024 * 2048 +        gate * 256 + mycol;
    const f16* Gr = G + (size_t)b * 1024 * 2048 + 1024 + gate * 256 + mycol;
    float* outf = out + (size_t)b * 1024 * 512 +       mycol;
    float* outr = out + (size_t)b * 1024 * 512 + 256 + mycol;

    float xwf = (float)Gf[0];
    float xwr = (float)Gr[(size_t)1023 * 2048];
    float cf = 0.f, cr = 0.f;                       // c_state per dir (quad-repl)
    __syncthreads();

    const char* hqb = (const char*)hq;
    signed char* hqw = (signed char*)hq;
    const int arow = (lane >> 4) << 4;              // A-frag byte offset
    const int baddr = lane & ~3;                    // bpermute byte addr
    int p = 0;

    for (int t = 0; t < 1024; ++t) {
        const int tn = (t < 1023) ? (t + 1) : t;
        f16 xnf = Gf[(size_t)tn * 2048];            // prefetch next xW (both dirs)
        f16 xnr = Gr[(size_t)(1023 - tn) * 2048];

        // ---- MFMA fwd (matrix pipe) ----
        i32x4 af0 = {0,0,0,0}, af1 = {0,0,0,0}, af2 = {0,0,0,0}, af3 = {0,0,0,0};
        #pragma unroll
        for (int ks = 0; ks < 4; ++ks) {
            i32x4 a = *(const i32x4*)(hqb + p * 256 + ks * 64 + arow);
            af0 = __builtin_amdgcn_mfma_i32_16x16x64_i8(a, uff[ 0 + ks], af0, 0, 0, 0);
            af1 = __builtin_amdgcn_mfma_i32_16x16x64_i8(a, uff[ 4 + ks], af1, 0, 0, 0);
            af2 = __builtin_amdgcn_mfma_i32_16x16x64_i8(a, uff[ 8 + ks], af2, 0, 0, 0);
            af3 = __builtin_amdgcn_mfma_i32_16x16x64_i8(a, uff[12 + ks], af3, 0, 0, 0);
        }
        // ---- MFMA rev (issues while fwd epilogue will run) ----
        i32x4 ar0 = {0,0,0,0}, ar1 = {0,0,0,0}, ar2 = {0,0,0,0}, ar3 = {0,0,0,0};
        #pragma unroll
        for (int ks = 0; ks < 4; ++ks) {
            i32x4 a = *(const i32x4*)(hqb + 512 + p * 256 + ks * 64 + arow);
            ar0 = __builtin_amdgcn_mfma_i32_16x16x64_i8(a, ufr[ 0 + ks], ar0, 0, 0, 0);
            ar1 = __builtin_amdgcn_mfma_i32_16x16x64_i8(a, ufr[ 4 + ks], ar1, 0, 0, 0);
            ar2 = __builtin_amdgcn_mfma_i32_16x16x64_i8(a, ufr[ 8 + ks], ar2, 0, 0, 0);
            ar3 = __builtin_amdgcn_mfma_i32_16x16x64_i8(a, ufr[12 + ks], ar3, 0, 0, 0);
        }

        // ---- epilogue fwd (VALU, overlaps rev MFMA drain) ----
        {
            int r0 = __builtin_amdgcn_ds_bpermute(baddr, af0[0]);
            int r1 = __builtin_amdgcn_ds_bpermute(baddr, af1[0]);
            int r2 = __builtin_amdgcn_ds_bpermute(baddr, af2[0]);
            int r3 = __builtin_amdgcn_ds_bpermute(baddr, af3[0]);
            int iv01 = (gate & 1) ? r1 : r0;
            int iv23 = (gate & 1) ? r3 : r2;
            int iv   = (gate & 2) ? iv23 : iv01;
            float pre = (float)iv * uscf + xwf;
            float a2 = (gate == 2) ? (pre + pre) : -pre;
            float E  = __expf(a2);
            float r  = __fdividef(1.f, E + 1.f);
            float v  = (gate == 2) ? (1.f - 2.f * r) : r;
            float b0 = qb<0x00>(v), b1 = qb<0x55>(v), b2 = qb<0xAA>(v), b3 = qb<0xFF>(v);
            cf = b1 * cf + b0 * b2;
            float e2 = __expf(cf + cf);
            float th = 1.f - __fdividef(2.f, e2 + 1.f);
            float h  = b3 * th;
            if (gate == 0) outf[(size_t)t * 512] = h;
            if (gate == 1) hqw[(p ^ 1) * 256 + mycol] = (signed char)__float2int_rn(h * 127.f);
        }
        // ---- epilogue rev ----
        {
            int r0 = __builtin_amdgcn_ds_bpermute(baddr, ar0[0]);
            int r1 = __builtin_amdgcn_ds_bpermute(baddr, ar1[0]);
            int r2 = __builtin_amdgcn_ds_bpermute(baddr, ar2[0]);
            int r3 = __builtin_amdgcn_ds_bpermute(baddr, ar3[0]);
            int iv01 = (gate & 1) ? r1 : r0;
            int iv23 = (gate & 1) ? r3 : r2;
            int iv   = (gate & 2) ? iv23 : iv01;
            float pre = (float)iv * uscr + xwr;
            float a2 = (gate == 2) ? (pre + pre) : -pre;
            float E  = __expf(a2);
            float r  = __fdividef(1.f, E + 1.f);
            float v  = (gate == 2) ? (1.f - 2.f * r) : r;
            float b0 = qb<0x00>(v), b1 = qb<0x55>(v), b2 = qb<0xAA>(v), b3 = qb<0xFF>(v);
            cr = b1 * cr + b0 * b2;
            float e2 = __expf(cr + cr);
            float th = 1.f - __fdividef(2.f, e2 + 1.f);
            float h  = b3 * th;
            if (gate == 0) outr[(size_t)(1023 - t) * 512] = h;
            if (gate == 1) hqw[512 + (p ^ 1) * 256 + mycol] = (signed char)__float2int_rn(h * 127.f);
        }

        LGKM_BARRIER();                             // both new h visible
        p ^= 1;
        xwf = (float)xnf;
        xwr = (float)xnr;
    }
}

extern "C" void kernel_launch(void* const* d_in, const int* in_sizes, int n_in,
                              void* d_out, int out_size, void* d_ws, size_t ws_size,
                              hipStream_t stream) {
    const float* x  = (const float*)d_in[0];
    const float* Wf = (const float*)d_in[1];
    const float* Uf = (const float*)d_in[2];
    const float* bf = (const float*)d_in[3];
    const float* Wr = (const float*)d_in[4];
    const float* Ur = (const float*)d_in[5];
    const float* br = (const float*)d_in[6];
    float* out = (float*)d_out;

    char* ws = (char*)d_ws;
    unsigned int* UQm = (unsigned int*)ws;                      // 512 KB
    float* Uscale     = (float*)(ws + (size_t)512 * 1024);      // 8 KB
    f16* G            = (f16*)(ws + (size_t)1024 * 1024);       // 128 MB

    prep_uq_kernel<<<8, 256, 0, stream>>>(Uf, Ur, UQm, Uscale);
    dim3 gg(16, 256);
    proj_gemm_kernel<<<gg, 256, 0, stream>>>(x, Wf, Wr, bf, br, G);
    scan_kernel<<<32, 1024, 0, stream>>>(G, UQm, Uscale, out);
}

// Round 15
// 997.232 us; speedup vs baseline: 7.5978x; 7.5978x over previous
//
#include <hip/hip_runtime.h>
#include <hip/hip_bf16.h>

typedef _Float16 f16;
typedef _Float16 half8 __attribute__((ext_vector_type(8)));
typedef float f32x4 __attribute__((ext_vector_type(4)));
typedef int i32x4 __attribute__((ext_vector_type(4)));

// B=32, S=1024, D=256, H=256, 4H=1024
// Scan r15 (= r12 best + single-bpermute epilogue): i8-MFMA recurrent matmul,
// quad-gate epilogue, 1 lgkm-barrier/step, double-buffered h.
// Wave w owns tiles {g*16+w} (all 4 gates of h-cols w*16..w*16+15).
// Lane l = gate (l&3) of h-col w*16+(l>>2); quads combine via DPP quad_perm.
// Epilogue redistribution: all 64 lanes hold identical C rows, so lane group
// a=l>>4 pre-selects acc_a locally (3 cndmask) and one ds_bpermute pulls
// (col l>>2, gate l&3) from lane (l&3)*16 + (l>>2).

// ---------------- prep: per-column int8 quantization of U (mfma layout) -----
// UQm uint4 index: ((dir*64 + tile)*4 + ks)*64 + kg*16 + colr
//   holds k = ks*64 + kg*16 + {0..15} (16 int8) for col = tile*16 + colr.
__global__ void prep_uq_kernel(const float* __restrict__ Uf, const float* __restrict__ Ur,
                               unsigned int* __restrict__ UQm, float* __restrict__ Uscale)
{
    int idx = blockIdx.x * 256 + threadIdx.x;   // (dir, c)
    if (idx >= 2048) return;
    int dir = idx >> 10, c = idx & 1023;
    const float* U = dir ? Ur : Uf;
    float m = 0.f;
    for (int k = 0; k < 256; ++k) m = fmaxf(m, fabsf(U[k * 1024 + c]));
    float sinv = (m > 0.f) ? 127.f / m : 0.f;
    int tile = c >> 4, colr = c & 15;
    uint4* UQm4 = (uint4*)UQm;
    for (int ks = 0; ks < 4; ++ks) {
        #pragma unroll
        for (int kg = 0; kg < 4; ++kg) {
            unsigned int w[4];
            #pragma unroll
            for (int d = 0; d < 4; ++d) {
                unsigned int wd = 0;
                #pragma unroll
                for (int e = 0; e < 4; ++e) {
                    int k = ks * 64 + kg * 16 + d * 4 + e;
                    int q = __float2int_rn(U[k * 1024 + c] * sinv);
                    wd |= ((unsigned int)(q & 0xff)) << (8 * e);
                }
                w[d] = wd;
            }
            UQm4[((size_t)((dir * 64 + tile) * 4 + ks)) * 64 + kg * 16 + colr] =
                make_uint4(w[0], w[1], w[2], w[3]);
        }
    }
    Uscale[idx] = m / (127.f * 127.f);  // U-scale * h-dequant(1/127)
}

// ---------------- projection GEMM (unchanged, proven) -----------------------
__global__ __launch_bounds__(256) void proj_gemm_kernel(
    const float* __restrict__ x, const float* __restrict__ Wf, const float* __restrict__ Wr,
    const float* __restrict__ bfw, const float* __restrict__ brw, f16* __restrict__ G)
{
    const int nt = blockIdx.x;
    const int mt = blockIdx.y;
    const int m0 = mt * 128, n0 = nt * 128;
    const int dir = n0 >> 10, nin0 = n0 & 1023;
    const float* W   = dir ? Wr : Wf;
    const float* bia = dir ? brw : bfw;
    __shared__ f16 Asm[128][40];
    __shared__ f16 Bsm[128][40];
    const int t = threadIdx.x;
    const int lane = t & 63, wave = t >> 6;
    const int wr = wave >> 1, wc = wave & 1;
    f32x4 acc[4][4] = {};
    for (int k0 = 0; k0 < 256; k0 += 32) {
        #pragma unroll
        for (int e = 0; e < 16; ++e) {
            int idx = e * 256 + t;
            int r = idx >> 5, kk = idx & 31;
            Asm[r][kk] = (f16)x[(size_t)(m0 + r) * 256 + (k0 + kk)];
        }
        #pragma unroll
        for (int e = 0; e < 16; ++e) {
            int idx = e * 256 + t;
            int col = idx & 127, kr = idx >> 7;
            Bsm[col][kr] = (f16)W[(size_t)(k0 + kr) * 1024 + (nin0 + col)];
        }
        __syncthreads();
        const int l15 = lane & 15, kb = (lane >> 4) * 8;
        half8 af[4], bfr[4];
        #pragma unroll
        for (int fr = 0; fr < 4; ++fr) af[fr]  = *(const half8*)&Asm[wr * 64 + fr * 16 + l15][kb];
        #pragma unroll
        for (int fc = 0; fc < 4; ++fc) bfr[fc] = *(const half8*)&Bsm[wc * 64 + fc * 16 + l15][kb];
        #pragma unroll
        for (int fr = 0; fr < 4; ++fr)
            #pragma unroll
            for (int fc = 0; fc < 4; ++fc)
                acc[fr][fc] = __builtin_amdgcn_mfma_f32_16x16x32_f16(af[fr], bfr[fc], acc[fr][fc], 0, 0, 0);
        __syncthreads();
    }
    const int row4 = (lane >> 4) * 4, c15 = lane & 15;
    #pragma unroll
    for (int fr = 0; fr < 4; ++fr)
        #pragma unroll
        for (int fc = 0; fc < 4; ++fc) {
            int rbase = m0 + wr * 64 + fr * 16 + row4;
            int cidx  = n0 + wc * 64 + fc * 16 + c15;
            float bv = bia[cidx & 1023];
            #pragma unroll
            for (int i = 0; i < 4; ++i)
                G[(size_t)(rbase + i) * 2048 + cidx] = (f16)(acc[fr][fc][i] + bv);
        }
}

// ---------------- scan ------------------------------------------------------
template<int PAT>
__device__ __forceinline__ float qb(float v) {   // quad_perm broadcast
    return __int_as_float(__builtin_amdgcn_mov_dpp(__float_as_int(v), PAT, 0xF, 0xF, true));
}

#define LGKM_BARRIER() do { \
    asm volatile("s_waitcnt lgkmcnt(0)\n\ts_barrier" ::: "memory"); \
    __builtin_amdgcn_sched_barrier(0); \
} while (0)

__global__
__attribute__((amdgpu_flat_work_group_size(1024, 1024)))
__attribute__((amdgpu_waves_per_eu(4, 4)))
void scan_kernel(
    const f16* __restrict__ G, const unsigned int* __restrict__ UQm,
    const float* __restrict__ Uscale, float* __restrict__ out)
{
    const int wg = blockIdx.x;
    const int dir = wg >> 5, b = wg & 31;
    const int tid = threadIdx.x;
    const int wave = tid >> 6, lane = tid & 63;
    const int colq = lane >> 2, gate = lane & 3;    // lane -> (col, gate)
    const int mycol = wave * 16 + colq;

    __shared__ __align__(16) unsigned int hq[128];  // 2 bufs x 256B int8 h

    if (tid < 64) hq[tid] = 0u;                     // buf0 = h0 = 0

    // B-fragments: gate g of my h-cols -> tile g*16+wave (64 regs, AGPR-ok)
    const i32x4* UQm4 = (const i32x4*)UQm;
    i32x4 uf0[4], uf1[4], uf2[4], uf3[4];
    #pragma unroll
    for (int ks = 0; ks < 4; ++ks) {
        uf0[ks] = UQm4[((size_t)((dir * 64 + ( 0 + wave)) * 4 + ks)) * 64 + lane];
        uf1[ks] = UQm4[((size_t)((dir * 64 + (16 + wave)) * 4 + ks)) * 64 + lane];
        uf2[ks] = UQm4[((size_t)((dir * 64 + (32 + wave)) * 4 + ks)) * 64 + lane];
        uf3[ks] = UQm4[((size_t)((dir * 64 + (48 + wave)) * 4 + ks)) * 64 + lane];
    }

    // per-lane dequant scale for (gate, mycol)
    const float uscl = Uscale[dir * 1024 + gate * 256 + mycol];

    // per-lane xW stream: G[s][dir*1024 + gate*256 + mycol]
    const f16* Gl = G + (size_t)b * 1024 * 2048 + dir * 1024 + gate * 256 + mycol;
    float* outp = out + (size_t)b * 1024 * 512 + dir * 256 + mycol;

    const int s0 = dir ? 1023 : 0;
    float xw = (float)Gl[(size_t)s0 * 2048];
    float c_state = 0.f;                            // replicated per quad
    __syncthreads();

    const char* hqb = (const char*)hq;
    signed char* hqw = (signed char*)hq;
    const int arow = (lane >> 4) << 4;              // A-frag byte offset
    const int baddr = ((gate << 4) | colq) << 2;    // pull from lane gate*16+colq
    int p = 0;

    for (int t = 0; t < 1024; ++t) {
        const int s  = dir ? (1023 - t) : t;
        const int tn = (t < 1023) ? (t + 1) : t;
        const int sn = dir ? (1023 - tn) : tn;
        f16 xn = Gl[(size_t)sn * 2048];             // prefetch next xW

        // h @ U, exact i32: A = h broadcast across rows; all C rows identical
        i32x4 acc0 = {0,0,0,0}, acc1 = {0,0,0,0}, acc2 = {0,0,0,0}, acc3 = {0,0,0,0};
        #pragma unroll
        for (int ks = 0; ks < 4; ++ks) {
            i32x4 a = *(const i32x4*)(hqb + p * 256 + ks * 64 + arow);
            acc0 = __builtin_amdgcn_mfma_i32_16x16x64_i8(a, uf0[ks], acc0, 0, 0, 0);
            acc1 = __builtin_amdgcn_mfma_i32_16x16x64_i8(a, uf1[ks], acc1, 0, 0, 0);
            acc2 = __builtin_amdgcn_mfma_i32_16x16x64_i8(a, uf2[ks], acc2, 0, 0, 0);
            acc3 = __builtin_amdgcn_mfma_i32_16x16x64_i8(a, uf3[ks], acc3, 0, 0, 0);
        }

        // every lane holds acc_g[0] = pre(col lane&15, gate g) for g=0..3.
        // Lane group a = lane>>4 pre-selects acc_a; lane l pulls its
        // (col l>>2, gate l&3) from lane (l&3)*16 + (l>>2): 1 bpermute total.
        int sel01 = (lane & 16) ? acc1[0] : acc0[0];
        int sel23 = (lane & 16) ? acc3[0] : acc2[0];
        int sgv   = (lane & 32) ? sel23 : sel01;
        int iv = __builtin_amdgcn_ds_bpermute(baddr, sgv);

        float pre = (float)iv * uscl + xw;
        // unified nonlinearity: gate 2 -> tanh, else sigmoid
        float a2 = (gate == 2) ? (pre + pre) : -pre;
        float E  = __expf(a2);
        float r  = __fdividef(1.f, E + 1.f);
        float v  = (gate == 2) ? (1.f - 2.f * r) : r;
        // quad combine: b0=sig_i, b1=sig_f, b2=tanh_g, b3=sig_o
        float b0 = qb<0x00>(v), b1 = qb<0x55>(v), b2 = qb<0xAA>(v), b3 = qb<0xFF>(v);
        c_state = b1 * c_state + b0 * b2;
        float e2 = __expf(c_state + c_state);
        float th = 1.f - __fdividef(2.f, e2 + 1.f);
        float h  = b3 * th;

        if (gate == 0) outp[(size_t)s * 512] = h;
        if (gate == 1) hqw[(p ^ 1) * 256 + mycol] = (signed char)__float2int_rn(h * 127.f);

        LGKM_BARRIER();                             // new h visible to all
        p ^= 1;
        xw = (float)xn;
    }
}

extern "C" void kernel_launch(void* const* d_in, const int* in_sizes, int n_in,
                              void* d_out, int out_size, void* d_ws, size_t ws_size,
                              hipStream_t stream) {
    const float* x  = (const float*)d_in[0];
    const float* Wf = (const float*)d_in[1];
    const float* Uf = (const float*)d_in[2];
    const float* bf = (const float*)d_in[3];
    const float* Wr = (const float*)d_in[4];
    const float* Ur = (const float*)d_in[5];
    const float* br = (const float*)d_in[6];
    float* out = (float*)d_out;

    char* ws = (char*)d_ws;
    unsigned int* UQm = (unsigned int*)ws;                      // 512 KB
    float* Uscale     = (float*)(ws + (size_t)512 * 1024);      // 8 KB
    f16* G            = (f16*)(ws + (size_t)1024 * 1024);       // 128 MB

    prep_uq_kernel<<<8, 256, 0, stream>>>(Uf, Ur, UQm, Uscale);
    dim3 gg(16, 256);
    proj_gemm_kernel<<<gg, 256, 0, stream>>>(x, Wf, Wr, bf, br, G);
    scan_kernel<<<64, 1024, 0, stream>>>(G, UQm, Uscale, out);
}